// Round 1
// baseline (594.616 us; speedup 1.0000x reference)
//
#include <hip/hip_runtime.h>
#include <math.h>

// GMM EM, M=4 mixtures x G=4 gaussians, C=3, EM_ITERS=3, EPS=1e-4.
// Pipeline: stats0 -> params -> em -> params -> em -> params -> final.
// Segmented stats via LDS ds_add_f32 into 32 lane-copies (stride 161: bank =
// (copy+slot)%32, conflict-free), block results to partials[160][grid] with
// plain stores (no global atomics, no memset needed).

#define NTHR  256
#define NBLK  512          // grid for the heavy kernels
#define NCOPY 32           // LDS accumulator copies (threadIdx & 31)
#define CSTR  161          // copy stride in floats (160 slots + 1 pad)
#define SLOTS 160          // 16 clusters * 10 stats
#define EPS_F 1e-4f
#define LOG2PI3 5.5136311992280366f   // 3*ln(2*pi)

static __device__ __forceinline__ void stat_add(float* q, float w,
                                                float a, float b, float c) {
    float wa = w * a, wb = w * b, wc = w * c;
    atomicAdd(q + 0, w);
    atomicAdd(q + 1, wa);
    atomicAdd(q + 2, wb);
    atomicAdd(q + 3, wc);
    atomicAdd(q + 4, wa * a);
    atomicAdd(q + 5, wa * b);
    atomicAdd(q + 6, wa * c);
    atomicAdd(q + 7, wb * b);
    atomicAdd(q + 8, wb * c);
    atomicAdd(q + 9, wc * c);
}

// ---------- pass 1: initial resp = (m = label, g = n % 4) ----------
__global__ __launch_bounds__(NTHR) void k_stats0(const float* __restrict__ x,
                                                 const int* __restrict__ lab,
                                                 float* __restrict__ partials,
                                                 int N) {
    __shared__ __align__(16) float sacc[NCOPY * CSTR];
    for (int i = threadIdx.x; i < NCOPY * CSTR; i += NTHR) sacc[i] = 0.f;
    __syncthreads();
    float* my = &sacc[(threadIdx.x & (NCOPY - 1)) * CSTR];

    const int groups = N >> 2;
    const float4* x0p = (const float4*)x;
    const float4* x1p = (const float4*)(x + N);
    const float4* x2p = (const float4*)(x + 2 * N);
    const int4*   lp  = (const int4*)lab;
    const int stride = gridDim.x * NTHR;
    for (int i = blockIdx.x * NTHR + threadIdx.x; i < groups; i += stride) {
        float4 a = x0p[i], b = x1p[i], c = x2p[i];
        int4 m4 = lp[i];
        // pixel n = 4*i + j  ->  g = n % 4 = j (static per slot)
        stat_add(my + (m4.x * 40 +  0), 1.0f, a.x, b.x, c.x);
        stat_add(my + (m4.y * 40 + 10), 1.0f, a.y, b.y, c.y);
        stat_add(my + (m4.z * 40 + 20), 1.0f, a.z, b.z, c.z);
        stat_add(my + (m4.w * 40 + 30), 1.0f, a.w, b.w, c.w);
    }
    __syncthreads();
    if (threadIdx.x < SLOTS) {
        float s = 0.f;
        #pragma unroll
        for (int cp = 0; cp < NCOPY; ++cp) s += sacc[cp * CSTR + threadIdx.x];
        partials[(size_t)threadIdx.x * gridDim.x + blockIdx.x] = s;
    }
}

// ---------- params: reduce partials, 16x 3x3 invert, emit E-step coeffs ----------
// params layout per cluster t=(m*4+g), stride 12:
// [0..2]=P*mu, [3]=c0, [4..6]=-0.5*Pii, [7..9]=-Pij (01,02,12), [10..11]=pad
__global__ __launch_bounds__(1024) void k_params(const float* __restrict__ partials,
                                                 float* __restrict__ params,
                                                 int nb) {
    __shared__ float qs[4][SLOTS];
    __shared__ float sums[SLOTS];
    __shared__ float wtab[16];
    const int t = threadIdx.x & 255;
    const int q = threadIdx.x >> 8;          // 4 quarters over the block dim
    if (t < SLOTS) {
        const int per = nb >> 2;             // blocks per quarter
        const float4* p = (const float4*)(partials + (size_t)t * nb + q * per);
        float s = 0.f;
        #pragma unroll 8
        for (int i = 0; i < (per >> 2); ++i) {
            float4 v = p[i];
            s += (v.x + v.y) + (v.z + v.w);
        }
        qs[q][t] = s;
    }
    __syncthreads();
    if (threadIdx.x < SLOTS)
        sums[threadIdx.x] = qs[0][threadIdx.x] + qs[1][threadIdx.x]
                          + qs[2][threadIdx.x] + qs[3][threadIdx.x];
    __syncthreads();
    if (threadIdx.x < 16) wtab[threadIdx.x] = sums[threadIdx.x * 10] + EPS_F;
    __syncthreads();
    if (threadIdx.x < 16) {
        const int tt = threadIdx.x;
        const float* S = &sums[tt * 10];
        const float w  = wtab[tt];
        const float iw = 1.0f / w;
        float mu0 = S[1] * iw, mu1 = S[2] * iw, mu2 = S[3] * iw;
        float c00 = S[4] * iw - mu0 * mu0 + EPS_F;
        float c01 = S[5] * iw - mu0 * mu1;
        float c02 = S[6] * iw - mu0 * mu2;
        float c11 = S[7] * iw - mu1 * mu1 + EPS_F;
        float c12 = S[8] * iw - mu1 * mu2;
        float c22 = S[9] * iw - mu2 * mu2 + EPS_F;
        float d00 = c11 * c22 - c12 * c12;
        float d01 = c02 * c12 - c01 * c22;
        float d02 = c01 * c12 - c02 * c11;
        float det = c00 * d00 + c01 * d01 + c02 * d02;
        float idet = 1.0f / det;
        float P00 = d00 * idet, P01 = d01 * idet, P02 = d02 * idet;
        float P11 = (c00 * c22 - c02 * c02) * idet;
        float P12 = (c01 * c02 - c00 * c12) * idet;
        float P22 = (c00 * c11 - c01 * c01) * idet;
        float logdet = logf(det);
        const int mb = tt & 12;              // m*4
        float wsum = wtab[mb] + wtab[mb + 1] + wtab[mb + 2] + wtab[mb + 3];
        float logpi = logf(w) - logf(wsum);
        float pm0 = P00 * mu0 + P01 * mu1 + P02 * mu2;
        float pm1 = P01 * mu0 + P11 * mu1 + P12 * mu2;
        float pm2 = P02 * mu0 + P12 * mu1 + P22 * mu2;
        float mPm = mu0 * pm0 + mu1 * pm1 + mu2 * pm2;
        float c0 = logpi - 0.5f * (mPm + logdet + LOG2PI3);
        float* P = params + tt * 12;
        P[0] = pm0; P[1] = pm1; P[2] = pm2; P[3] = c0;
        P[4] = -0.5f * P00; P[5] = -0.5f * P11; P[6] = -0.5f * P22;
        P[7] = -P01; P[8] = -P02; P[9] = -P12;
        P[10] = 0.f; P[11] = 0.f;
    }
}

// ---------- fused E-step (own mixture only) + M-step stats ----------
static __device__ __forceinline__ void em_pixel(const float* __restrict__ spar,
                                                float* my,
                                                float a, float b, float c, int m) {
    const float* P0 = spar + m * 48;
    float xx00 = a * a, xx01 = a * b, xx02 = a * c;
    float xx11 = b * b, xx12 = b * c, xx22 = c * c;
    float l[4];
    #pragma unroll
    for (int g = 0; g < 4; ++g) {
        const float* P = P0 + g * 12;
        float4 q0 = *(const float4*)(P);
        float4 q1 = *(const float4*)(P + 4);
        float2 q2 = *(const float2*)(P + 8);
        l[g] = q0.w + q0.x * a + q0.y * b + q0.z * c
             + q1.x * xx00 + q1.y * xx11 + q1.z * xx22
             + q1.w * xx01 + q2.x * xx02 + q2.y * xx12;
    }
    float mx = fmaxf(fmaxf(l[0], l[1]), fmaxf(l[2], l[3]));
    float e0 = __expf(l[0] - mx), e1 = __expf(l[1] - mx);
    float e2 = __expf(l[2] - mx), e3 = __expf(l[3] - mx);
    float rs = 1.0f / (e0 + e1 + e2 + e3);
    float* q = my + m * 40;
    stat_add(q +  0, e0 * rs, a, b, c);
    stat_add(q + 10, e1 * rs, a, b, c);
    stat_add(q + 20, e2 * rs, a, b, c);
    stat_add(q + 30, e3 * rs, a, b, c);
}

__global__ __launch_bounds__(NTHR) void k_em(const float* __restrict__ x,
                                             const int* __restrict__ lab,
                                             const float* __restrict__ params,
                                             float* __restrict__ partials,
                                             int N) {
    __shared__ __align__(16) float sacc[NCOPY * CSTR];
    __shared__ __align__(16) float spar[192];
    for (int i = threadIdx.x; i < NCOPY * CSTR; i += NTHR) sacc[i] = 0.f;
    if (threadIdx.x < 192) spar[threadIdx.x] = params[threadIdx.x];
    __syncthreads();
    float* my = &sacc[(threadIdx.x & (NCOPY - 1)) * CSTR];

    const int groups = N >> 2;
    const float4* x0p = (const float4*)x;
    const float4* x1p = (const float4*)(x + N);
    const float4* x2p = (const float4*)(x + 2 * N);
    const int4*   lp  = (const int4*)lab;
    const int stride = gridDim.x * NTHR;
    for (int i = blockIdx.x * NTHR + threadIdx.x; i < groups; i += stride) {
        float4 a = x0p[i], b = x1p[i], c = x2p[i];
        int4 m4 = lp[i];
        em_pixel(spar, my, a.x, b.x, c.x, m4.x);
        em_pixel(spar, my, a.y, b.y, c.y, m4.y);
        em_pixel(spar, my, a.z, b.z, c.z, m4.z);
        em_pixel(spar, my, a.w, b.w, c.w, m4.w);
    }
    __syncthreads();
    if (threadIdx.x < SLOTS) {
        float s = 0.f;
        #pragma unroll
        for (int cp = 0; cp < NCOPY; ++cp) s += sacc[cp * CSTR + threadIdx.x];
        partials[(size_t)threadIdx.x * gridDim.x + blockIdx.x] = s;
    }
}

// ---------- final: logp for all 16 gaussians -> logsumexp_g -> softmax_m ----------
static __device__ __forceinline__ void final_pixel(const float* __restrict__ PR,
                                                   float a, float b, float c,
                                                   float* post) {
    float xx00 = a * a, xx01 = a * b, xx02 = a * c;
    float xx11 = b * b, xx12 = b * c, xx22 = c * c;
    float ml[4];
    #pragma unroll
    for (int m = 0; m < 4; ++m) {
        float l[4];
        #pragma unroll
        for (int g = 0; g < 4; ++g) {
            const float* P = PR + (m * 4 + g) * 10;
            l[g] = P[3] + P[0] * a + P[1] * b + P[2] * c
                 + P[4] * xx00 + P[5] * xx11 + P[6] * xx22
                 + P[7] * xx01 + P[8] * xx02 + P[9] * xx12;
        }
        float mx = fmaxf(fmaxf(l[0], l[1]), fmaxf(l[2], l[3]));
        ml[m] = mx + __logf(__expf(l[0] - mx) + __expf(l[1] - mx)
                          + __expf(l[2] - mx) + __expf(l[3] - mx));
    }
    float mmx = fmaxf(fmaxf(ml[0], ml[1]), fmaxf(ml[2], ml[3]));
    float e0 = __expf(ml[0] - mmx), e1 = __expf(ml[1] - mmx);
    float e2 = __expf(ml[2] - mmx), e3 = __expf(ml[3] - mmx);
    float rs = 1.0f / (e0 + e1 + e2 + e3);
    post[0] = e0 * rs; post[1] = e1 * rs; post[2] = e2 * rs; post[3] = e3 * rs;
}

__global__ __launch_bounds__(NTHR) void k_final(const float* __restrict__ x,
                                                const float* __restrict__ params,
                                                float* __restrict__ out,
                                                int N) {
    __shared__ __align__(16) float spar[192];
    if (threadIdx.x < 192) spar[threadIdx.x] = params[threadIdx.x];
    __syncthreads();
    // hoist params into registers (static indexing only after full unroll)
    float PR[160];
    #pragma unroll
    for (int t = 0; t < 16; ++t) {
        #pragma unroll
        for (int k = 0; k < 10; ++k) PR[t * 10 + k] = spar[t * 12 + k];
    }
    const int groups = N >> 2;
    const float4* x0p = (const float4*)x;
    const float4* x1p = (const float4*)(x + N);
    const float4* x2p = (const float4*)(x + 2 * N);
    const int stride = gridDim.x * NTHR;
    for (int i = blockIdx.x * NTHR + threadIdx.x; i < groups; i += stride) {
        float4 a = x0p[i], b = x1p[i], c = x2p[i];
        float p0[4], p1[4], p2[4], p3[4];
        final_pixel(PR, a.x, b.x, c.x, p0);
        final_pixel(PR, a.y, b.y, c.y, p1);
        final_pixel(PR, a.z, b.z, c.z, p2);
        final_pixel(PR, a.w, b.w, c.w, p3);
        #pragma unroll
        for (int m = 0; m < 4; ++m) {
            ((float4*)(out + (size_t)m * N))[i] =
                make_float4(p0[m], p1[m], p2[m], p3[m]);
        }
    }
}

extern "C" void kernel_launch(void* const* d_in, const int* in_sizes, int n_in,
                              void* d_out, int out_size, void* d_ws, size_t ws_size,
                              hipStream_t stream) {
    const float* x   = (const float*)d_in[0];   // [3, N] float32
    const int*   lab = (const int*)d_in[1];     // [N] int32 in [0,4)
    float* out = (float*)d_out;                 // [4, N] float32
    const int N = in_sizes[1];

    int nb = NBLK;
    if (ws_size < (size_t)(SLOTS * NBLK + 192) * sizeof(float)) nb = 128;
    float* partials = (float*)d_ws;             // [160][nb]
    float* params   = partials + (size_t)SLOTS * nb;  // [16*12]

    dim3 grid(nb), blk(NTHR);
    k_stats0<<<grid, blk, 0, stream>>>(x, lab, partials, N);
    k_params<<<dim3(1), dim3(1024), 0, stream>>>(partials, params, nb);
    k_em<<<grid, blk, 0, stream>>>(x, lab, params, partials, N);
    k_params<<<dim3(1), dim3(1024), 0, stream>>>(partials, params, nb);
    k_em<<<grid, blk, 0, stream>>>(x, lab, params, partials, N);
    k_params<<<dim3(1), dim3(1024), 0, stream>>>(partials, params, nb);
    k_final<<<grid, blk, 0, stream>>>(x, params, out, N);
}